// Round 10
// baseline (1987.058 us; speedup 1.0000x reference)
//
#include <hip/hip_runtime.h>
#include <stdint.h>

// ResidualVQ on MI355X — round 10: hot loop purged of LDS state.
// R f32 -> global g_resid (L2-hot per-block slices); Rb bf16 mirror in LDS
// for A-frags; register running-min + 4-chunk-cadence rminU sync; dbuf
// global_load_lds staging kept; 52KB LDS -> 3 blocks/CU (6 waves).
// Contract (proven rounds 4-9): indices match numpy argmin of
// d = fl(fl(t1+nk) - fl(2*dot)); np-exact pairwise sumsq trees; serial
// ascending-k single-accumulator FMA rescore; stale-threshold prefilter with
// delta = 0.02*sqrt(t1)*sqrt(nkmax) + 3e-4 >= 2*E_bf16 (any stale min >= the
// global est-min keeps the true argmin inside the window).
// g_wb stored PRE-PERMUTED (16B slot s -> s^(code&7) per 512B code row).

#define NQ      8
#define KCODES  1024
#define DIM     256
#define NVEC    65536
#define ROWS    32
#define RSTB    264      // Rb row stride (bf16): 528B -> spread banks
#define CCH     32       // codes per staged chunk (16 KB per buffer)
#define NCH     (KCODES / CCH)   // 32 chunks
#define WARM    8        // min-only chunks (revisited at the end)
#define CAP     24       // candidate capacity per row per q

typedef unsigned int u32;
typedef unsigned long long u64;
typedef unsigned short u16;
typedef short bf16x8 __attribute__((ext_vector_type(8)));
typedef float f32x4  __attribute__((ext_vector_type(4)));

__device__ float  g_norms[NQ * KCODES];
__device__ u32    g_nkmax;
__device__ double g_loss;
__device__ __align__(16) u16 g_wb[(size_t)NQ * KCODES * DIM];  // permuted bf16
__device__ float  g_resid[(size_t)NVEC * DIM];                 // f32 residual

__device__ __forceinline__ u16 bf16rne(float x){
    u32 u = __float_as_uint(x);
    return (u16)((u + 0x7FFFu + ((u >> 16) & 1u)) >> 16);
}

__device__ __forceinline__ u64 pack4(float4 v){
    return  (u64)bf16rne(v.x)        | ((u64)bf16rne(v.y) << 16)
         | ((u64)bf16rne(v.z) << 32) | ((u64)bf16rne(v.w) << 48);
}

__device__ __forceinline__ void gload_lds16(const void* g, void* l){
    __builtin_amdgcn_global_load_lds(
        (const __attribute__((address_space(1))) u32*)g,
        (__attribute__((address_space(3))) u32*)l, 16, 0, 0);
}

// numpy pairwise sum of squares over 128 contiguous floats (verified round 4)
__device__ __forceinline__ float np_sumsq128(const float* __restrict__ a){
    float r0,r1,r2,r3,r4,r5,r6,r7;
    {
        float4 v0 = *(const float4*)(a);
        float4 v1 = *(const float4*)(a + 4);
        r0 = __fmul_rn(v0.x,v0.x); r1 = __fmul_rn(v0.y,v0.y);
        r2 = __fmul_rn(v0.z,v0.z); r3 = __fmul_rn(v0.w,v0.w);
        r4 = __fmul_rn(v1.x,v1.x); r5 = __fmul_rn(v1.y,v1.y);
        r6 = __fmul_rn(v1.z,v1.z); r7 = __fmul_rn(v1.w,v1.w);
    }
    for (int i = 8; i < 128; i += 8){
        float4 v0 = *(const float4*)(a + i);
        float4 v1 = *(const float4*)(a + i + 4);
        r0 = __fadd_rn(r0, __fmul_rn(v0.x,v0.x));
        r1 = __fadd_rn(r1, __fmul_rn(v0.y,v0.y));
        r2 = __fadd_rn(r2, __fmul_rn(v0.z,v0.z));
        r3 = __fadd_rn(r3, __fmul_rn(v0.w,v0.w));
        r4 = __fadd_rn(r4, __fmul_rn(v1.x,v1.x));
        r5 = __fadd_rn(r5, __fmul_rn(v1.y,v1.y));
        r6 = __fadd_rn(r6, __fmul_rn(v1.z,v1.z));
        r7 = __fadd_rn(r7, __fmul_rn(v1.w,v1.w));
    }
    return __fadd_rn(__fadd_rn(__fadd_rn(r0,r1), __fadd_rn(r2,r3)),
                     __fadd_rn(__fadd_rn(r4,r5), __fadd_rn(r6,r7)));
}

__global__ void vq_zero(){ g_loss = 0.0; g_nkmax = 0u; }

__global__ void vq_norms_np(const float* __restrict__ cb){
    int row = blockIdx.x * 256 + threadIdx.x;               // 8192 rows
    const float* a = cb + (size_t)row * DIM;
    float n = __fadd_rn(np_sumsq128(a), np_sumsq128(a + 128));
    g_norms[row] = n;
    atomicMax(&g_nkmax, __float_as_uint(n));
}

// bf16 convert + intra-row 16B-slot permutation: slot s -> s ^ (code&7)
__global__ void vq_prep_wb(const float* __restrict__ cb){
    int t = blockIdx.x * 256 + threadIdx.x;     // 262,144 = 8192 codes x 32 slots
    int code = t >> 5, s = t & 31;
    const float* src = cb + (size_t)code * DIM + s * 8;
    float4 v0 = *(const float4*)(src);
    float4 v1 = *(const float4*)(src + 4);
    u64* dst = (u64*)(g_wb + (size_t)code * DIM + ((s ^ (code & 7)) << 3));
    dst[0] = pack4(v0); dst[1] = pack4(v1);
}

__device__ __forceinline__ void ldsAtomicMinU64(u64* p, u64 v){
    u64 old = *p;
    while (v < old){
        u64 a = old;
        old = atomicCAS(p, a, v);
        if (old == a) break;
    }
}

__global__ __launch_bounds__(128)
void vq_main(const float* __restrict__ z, const float* __restrict__ cb,
             float* __restrict__ out)
{
    __shared__ __align__(16) u16 Rb[ROWS * RSTB];     // 16,896 B bf16 residual
    __shared__ __align__(16) u16 Wst[2][CCH * DIM];   // 32,768 B double buffer
    __shared__ float t1[ROWS];
    __shared__ u32   rminU[ROWS];
    __shared__ u32   cnt[ROWS];
    __shared__ u16   cand[ROWS * CAP];                //  1,536 B
    __shared__ u64   bestKey[ROWS];
    __shared__ int   off[ROWS + 1];
    __shared__ int   totalS, ovf;                     // ~52 KB -> 3 blocks/CU

    const int tid     = threadIdx.x;                  // 128 threads, 2 waves
    const int rowbase = blockIdx.x * ROWS;
    const int ct      = tid >> 6;                     // wave id = codetile 0/1
    const int lane    = tid & 63;
    const int l15     = lane & 15, lg = lane >> 4;
    const int key     = l15 & 7;
    const int urow    = tid >> 2, us = tid & 3;       // update map: 4 thr/row
    double lossAcc = 0.0;

    // prologue: Rb <- bf16(z)
#pragma unroll
    for (int l = 0; l < 16; ++l){
        int i = l * 128 + tid;              // 2048 f4 = 32 rows x 64
        int row = i >> 6, c4 = i & 63;
        float4 v = *(const float4*)(z + (size_t)(rowbase + row) * DIM + c4 * 4);
        *(u64*)(Rb + row * RSTB + c4 * 4) = pack4(v);
    }

    const float sqnkmax = sqrtf(__uint_as_float(g_nkmax));

    for (int q = 0; q < NQ; ++q){
        const float* rsrc = q ? (const float*)g_resid : z;
        const char*  wbq  = (const char*)g_wb + (size_t)q * KCODES * DIM * 2;

        // issue stage chunk0 -> buf0 (drains at the barrier below)
        {
            char* d = (char*)Wst[0];
#pragma unroll
            for (int r = 0; r < 8; ++r){
                int o = (r * 128 + tid) * 16;
                gload_lds16(wbq + o, d + o);
            }
        }
        // t1 (np-exact, from global residual) + state reset
        if (tid < 64){
            float s = np_sumsq128(rsrc + (size_t)(rowbase + (tid >> 1)) * DIM
                                  + (tid & 1) * 128);
            float o = __shfl_xor(s, 1);
            if (!(tid & 1)) t1[tid >> 1] = __fadd_rn(s, o);
        }
        if (tid < ROWS){
            rminU[tid]   = 0x7f800000u;
            cnt[tid]     = 0u;
            bestKey[tid] = ~0ull;
        }
        __syncthreads();
        if (tid == 0 && q > 0)
            for (int r = 0; r < ROWS; ++r) lossAcc += (double)t1[r];

        // A-frags from Rb (already bf16)
        bf16x8 a[2][8];
#pragma unroll
        for (int rt = 0; rt < 2; ++rt){
            const u16* rr = Rb + (rt * 16 + l15) * RSTB;
#pragma unroll
            for (int ks = 0; ks < 8; ++ks)
                a[rt][ks] = *(const bf16x8*)(rr + lg * 8 + ks * 32);
        }
        float t1r[2][4], delta[2][4], mloc[2][4], thr[2][4];
#pragma unroll
        for (int rt = 0; rt < 2; ++rt)
#pragma unroll
            for (int j = 0; j < 4; ++j){
                t1r[rt][j]   = t1[rt * 16 + lg * 4 + j];
                delta[rt][j] = 0.02f * sqrtf(t1r[rt][j]) * sqnkmax + 3e-4f;
                mloc[rt][j]  = __int_as_float(0x7f800000);
                thr[rt][j]   = -1.0f;   // no collect until first refresh
            }

        // ---- chunk loop: dbuf staging, register-min, cadence-4 sync ----
        for (int tt = 0; tt < NCH + WARM; ++tt){
            int  cc      = (tt < NCH) ? tt : (tt - NCH);
            int  cur     = tt & 1;
            bool collect = (tt >= WARM);

            if (tt && (tt & 3) == 0){     // refresh thresholds from shared min
#pragma unroll
                for (int rt = 0; rt < 2; ++rt)
#pragma unroll
                    for (int j = 0; j < 4; ++j){
                        float g = __uint_as_float(rminU[rt * 16 + lg * 4 + j]);
                        thr[rt][j] = fminf(g, mloc[rt][j]) + delta[rt][j];
                    }
            }
            if (tt + 1 < NCH + WARM){     // issue-early: next chunk -> buf^1
                int nc = (tt + 1 < NCH) ? tt + 1 : (tt + 1 - NCH);
                const char* src = wbq + (size_t)nc * (CCH * DIM * 2);
                char* d = (char*)Wst[cur ^ 1];
#pragma unroll
                for (int r = 0; r < 8; ++r){
                    int o = (r * 128 + tid) * 16;
                    gload_lds16(src + o, d + o);
                }
            }

            int   codeL = ct * 16 + l15;
            float nk    = g_norms[q * KCODES + cc * CCH + codeL];
            const u16* wrow = Wst[cur] + codeL * DIM;
            f32x4 accA0 = {0,0,0,0}, accB0 = {0,0,0,0};
            f32x4 accA1 = {0,0,0,0}, accB1 = {0,0,0,0};
#pragma unroll
            for (int ks = 0; ks < 4; ++ks){
                bf16x8 blo = *(const bf16x8*)(wrow + (((ks * 4 + lg) ^ key) << 3));
                bf16x8 bhi = *(const bf16x8*)(wrow + ((((ks + 4) * 4 + lg) ^ key) << 3));
                accA0 = __builtin_amdgcn_mfma_f32_16x16x32_bf16(a[0][ks],     blo, accA0, 0, 0, 0);
                accB0 = __builtin_amdgcn_mfma_f32_16x16x32_bf16(a[0][ks + 4], bhi, accB0, 0, 0, 0);
                accA1 = __builtin_amdgcn_mfma_f32_16x16x32_bf16(a[1][ks],     blo, accA1, 0, 0, 0);
                accB1 = __builtin_amdgcn_mfma_f32_16x16x32_bf16(a[1][ks + 4], bhi, accB1, 0, 0, 0);
            }
            int codeg = cc * CCH + codeL;
#pragma unroll
            for (int rt = 0; rt < 2; ++rt){
                f32x4 sA = rt ? accA1 : accA0, sB = rt ? accB1 : accB0;
#pragma unroll
                for (int j = 0; j < 4; ++j){
                    float dest = (t1r[rt][j] + nk) - 2.0f * (sA[j] + sB[j]);
                    mloc[rt][j] = fminf(mloc[rt][j], dest);
                    if (collect && dest <= thr[rt][j]){
                        int row = rt * 16 + lg * 4 + j;
                        u32 slot = atomicAdd(&cnt[row], 1u);
                        if (slot < CAP) cand[row * CAP + slot] = (u16)codeg;
                    }
                }
            }
            if ((tt & 3) == 3){           // publish wave-min to rminU
                float m[2][4];
#pragma unroll
                for (int rt = 0; rt < 2; ++rt)
#pragma unroll
                    for (int j = 0; j < 4; ++j) m[rt][j] = mloc[rt][j];
#pragma unroll
                for (int msk = 1; msk < 16; msk <<= 1)
#pragma unroll
                    for (int rt = 0; rt < 2; ++rt)
#pragma unroll
                        for (int j = 0; j < 4; ++j)
                            m[rt][j] = fminf(m[rt][j], __shfl_xor(m[rt][j], msk));
                if (l15 == 0){
#pragma unroll
                    for (int rt = 0; rt < 2; ++rt)
#pragma unroll
                        for (int j = 0; j < 4; ++j)
                            atomicMin(&rminU[rt * 16 + lg * 4 + j],
                                      __float_as_uint(m[rt][j]));
                }
            }
            __syncthreads();
        }

        // ---- task offsets: wave-parallel scan over 32 rows ----
        if (tid < 64){
            int c    = (tid < 32) ? min((int)cnt[tid], CAP) : 0;
            int over = (tid < 32) ? (cnt[tid] > CAP) : 0;
            int x = c;
#pragma unroll
            for (int o = 1; o < 32; o <<= 1){
                int y = __shfl_up(x, o);
                if (tid >= o) x += y;
            }
            if (tid < 32) off[tid] = x - c;
            if (tid == 31){ off[32] = x; totalS = x; }
#pragma unroll
            for (int o = 1; o < 32; o <<= 1) over |= __shfl_xor(over, o);
            if (tid == 0) ovf = over;
        }
        __syncthreads();

        // ---- exact rescore (round-4-identical serial FMA chain) ----
        int nT = totalS;
        for (int t = tid; t < nT; t += 128){
            int r = 0;
            while (off[r + 1] <= t) ++r;
            int k = (int)cand[r * CAP + (t - off[r])];
            const float* wr = cb + ((size_t)q * KCODES + k) * DIM;
            const float* rr = rsrc + (size_t)(rowbase + r) * DIM;
            float dot = 0.f;
#pragma unroll 4
            for (int i = 0; i < 64; ++i){
                float4 rv = *(const float4*)(rr + i * 4);
                float4 wv = *(const float4*)(wr + i * 4);
                dot = __builtin_fmaf(rv.x, wv.x, dot);
                dot = __builtin_fmaf(rv.y, wv.y, dot);
                dot = __builtin_fmaf(rv.z, wv.z, dot);
                dot = __builtin_fmaf(rv.w, wv.w, dot);
            }
            float d = __fsub_rn(__fadd_rn(t1[r], g_norms[q * KCODES + k]),
                                __fmul_rn(2.0f, dot));
            ldsAtomicMinU64(&bestKey[r], ((u64)__float_as_uint(d) << 32) | (u32)k);
        }
        if (ovf){   // correctness fallback; rare
            for (int r = 0; r < ROWS; ++r){
                if (cnt[r] > CAP){
                    for (int k = tid; k < KCODES; k += 128){
                        const float* wr = cb + ((size_t)q * KCODES + k) * DIM;
                        const float* rr = rsrc + (size_t)(rowbase + r) * DIM;
                        float dot = 0.f;
                        for (int i = 0; i < 64; ++i){
                            float4 rv = *(const float4*)(rr + i * 4);
                            float4 wv = *(const float4*)(wr + i * 4);
                            dot = __builtin_fmaf(rv.x, wv.x, dot);
                            dot = __builtin_fmaf(rv.y, wv.y, dot);
                            dot = __builtin_fmaf(rv.z, wv.z, dot);
                            dot = __builtin_fmaf(rv.w, wv.w, dot);
                        }
                        float d = __fsub_rn(__fadd_rn(t1[r], g_norms[q * KCODES + k]),
                                            __fmul_rn(2.0f, dot));
                        ldsAtomicMinU64(&bestKey[r], ((u64)__float_as_uint(d) << 32) | (u32)k);
                    }
                }
            }
        }
        __syncthreads();

        // indices out (f32) directly
        if (tid < ROWS)
            out[(size_t)NVEC * DIM + (size_t)(rowbase + tid) * NQ + q] =
                (float)(int)(bestKey[tid] & 0xFFFFFFFFull);

        // update: r_new = fl(r - fl(r + fl(zq - r))) -> g_resid (f32) + Rb (bf16)
        {
            int k = (int)(bestKey[urow] & 0xFFFFFFFFull);
            const float* wrow = cb + ((size_t)q * KCODES + k) * DIM;
            const float* rrow = rsrc + (size_t)(rowbase + urow) * DIM;
            float*       grow = g_resid + (size_t)(rowbase + urow) * DIM;
            u16*         brow = Rb + urow * RSTB;
#pragma unroll
            for (int j = 0; j < 16; ++j){
                int d0 = us * 4 + j * 16;
                float4 r4 = *(const float4*)(rrow + d0);
                float4 wv = *(const float4*)(wrow + d0);
                float4 rn;
                rn.x = __fsub_rn(r4.x, __fadd_rn(r4.x, __fsub_rn(wv.x, r4.x)));
                rn.y = __fsub_rn(r4.y, __fadd_rn(r4.y, __fsub_rn(wv.y, r4.y)));
                rn.z = __fsub_rn(r4.z, __fadd_rn(r4.z, __fsub_rn(wv.z, r4.z)));
                rn.w = __fsub_rn(r4.w, __fadd_rn(r4.w, __fsub_rn(wv.w, r4.w)));
                *(float4*)(grow + d0) = rn;
                *(u64*)(brow + d0)    = pack4(rn);
            }
        }
        __syncthreads();   // Rb + g_resid visible for next q
    }

    // final residual norm (r_8) -> loss
    if (tid < 64){
        float s = np_sumsq128(g_resid + (size_t)(rowbase + (tid >> 1)) * DIM
                              + (tid & 1) * 128);
        float o = __shfl_xor(s, 1);
        if (!(tid & 1)) t1[tid >> 1] = __fadd_rn(s, o);
    }
    __syncthreads();
    if (tid == 0){
        for (int r = 0; r < ROWS; ++r) lossAcc += (double)t1[r];
        atomicAdd(&g_loss, lossAcc);
    }

    // recon out (f32): z - r_final
#pragma unroll
    for (int l = 0; l < 16; ++l){
        int i = l * 128 + tid;
        int row = i >> 6, c4 = i & 63;
        size_t base = (size_t)(rowbase + row) * DIM + c4 * 4;
        float4 zv = *(const float4*)(z + base);
        float4 rv = *(const float4*)(g_resid + base);
        float4 ov;
        ov.x = __fsub_rn(zv.x, rv.x);
        ov.y = __fsub_rn(zv.y, rv.y);
        ov.z = __fsub_rn(zv.z, rv.z);
        ov.w = __fsub_rn(zv.w, rv.w);
        *(float4*)(out + base) = ov;
    }
}

__global__ void vq_loss_final(float* __restrict__ out){
    if (threadIdx.x == 0 && blockIdx.x == 0){
        double m = 1.25 * g_loss / ((double)NVEC * (double)DIM);
        out[(size_t)NVEC * DIM + (size_t)NVEC * NQ] = (float)m;
    }
}

extern "C" void kernel_launch(void* const* d_in, const int* in_sizes, int n_in,
                              void* d_out, int out_size, void* d_ws, size_t ws_size,
                              hipStream_t stream) {
    (void)in_sizes; (void)n_in; (void)out_size; (void)d_ws; (void)ws_size;
    const float* z  = (const float*)d_in[0];
    const float* cb = (const float*)d_in[1];
    float* out = (float*)d_out;

    hipLaunchKernelGGL(vq_zero,       dim3(1),    dim3(1),   0, stream);
    hipLaunchKernelGGL(vq_norms_np,   dim3(32),   dim3(256), 0, stream, cb);
    hipLaunchKernelGGL(vq_prep_wb,    dim3(1024), dim3(256), 0, stream, cb);
    hipLaunchKernelGGL(vq_main,       dim3(NVEC / ROWS), dim3(128), 0, stream, z, cb, out);
    hipLaunchKernelGGL(vq_loss_final, dim3(1),    dim3(64),  0, stream, out);
}

// Round 11
// 1261.438 us; speedup vs baseline: 1.5752x; 1.5752x over previous
//
#include <hip/hip_runtime.h>
#include <stdint.h>

// ResidualVQ on MI355X — round 11: occupancy-first redesign.
// 64 rows/block, 4 waves x (16 rows x 16 codes) tiles, LDS ~25KB ->
// 4 blocks/CU = 4 waves/SIMD (round 7-10 were 1 wave/SIMD, latency-bound).
// A-frags built from L2-hot g_resid (no LDS residual mirror); Wst dbuf
// 2x8KB global_load_lds; register running-min + cadence-4 rminU publish.
// Contract (proven rounds 4-10): indices match numpy argmin of
// d = fl(fl(t1+nk) - fl(2*dot)); np-exact pairwise sumsq trees; serial
// ascending-k single-accumulator FMA rescore; stale-threshold prefilter,
// delta = 0.02*sqrt(t1)*sqrt(nkmax) + 3e-4 >= 2*E_bf16 (stale min >= true
// min keeps the argmin inside the window).
// g_wb PRE-PERMUTED (16B slot s -> s^(code&7) per 512B code row).

#define NQ      8
#define KCODES  1024
#define DIM     256
#define NVEC    65536
#define ROWS    64
#define CCH     16       // codes per staged chunk (8 KB per buffer)
#define NCH     (KCODES / CCH)   // 64 chunks
#define WARM    8        // min-only chunks (revisited at the end)
#define CAP     24       // candidate capacity per row per q

typedef unsigned int u32;
typedef unsigned long long u64;
typedef unsigned short u16;
typedef short bf16x8 __attribute__((ext_vector_type(8)));
typedef float f32x4  __attribute__((ext_vector_type(4)));

__device__ float  g_norms[NQ * KCODES];
__device__ u32    g_nkmax;
__device__ double g_loss;
__device__ __align__(16) u16 g_wb[(size_t)NQ * KCODES * DIM];  // permuted bf16
__device__ float  g_resid[(size_t)NVEC * DIM];                 // f32 residual

__device__ __forceinline__ u16 bf16rne(float x){
    u32 u = __float_as_uint(x);
    return (u16)((u + 0x7FFFu + ((u >> 16) & 1u)) >> 16);
}

__device__ __forceinline__ u64 pack4(float4 v){
    return  (u64)bf16rne(v.x)        | ((u64)bf16rne(v.y) << 16)
         | ((u64)bf16rne(v.z) << 32) | ((u64)bf16rne(v.w) << 48);
}

__device__ __forceinline__ void gload_lds16(const void* g, void* l){
    __builtin_amdgcn_global_load_lds(
        (const __attribute__((address_space(1))) u32*)g,
        (__attribute__((address_space(3))) u32*)l, 16, 0, 0);
}

// numpy pairwise sum of squares over 128 contiguous floats (verified round 4)
__device__ __forceinline__ float np_sumsq128(const float* __restrict__ a){
    float r0,r1,r2,r3,r4,r5,r6,r7;
    {
        float4 v0 = *(const float4*)(a);
        float4 v1 = *(const float4*)(a + 4);
        r0 = __fmul_rn(v0.x,v0.x); r1 = __fmul_rn(v0.y,v0.y);
        r2 = __fmul_rn(v0.z,v0.z); r3 = __fmul_rn(v0.w,v0.w);
        r4 = __fmul_rn(v1.x,v1.x); r5 = __fmul_rn(v1.y,v1.y);
        r6 = __fmul_rn(v1.z,v1.z); r7 = __fmul_rn(v1.w,v1.w);
    }
    for (int i = 8; i < 128; i += 8){
        float4 v0 = *(const float4*)(a + i);
        float4 v1 = *(const float4*)(a + i + 4);
        r0 = __fadd_rn(r0, __fmul_rn(v0.x,v0.x));
        r1 = __fadd_rn(r1, __fmul_rn(v0.y,v0.y));
        r2 = __fadd_rn(r2, __fmul_rn(v0.z,v0.z));
        r3 = __fadd_rn(r3, __fmul_rn(v0.w,v0.w));
        r4 = __fadd_rn(r4, __fmul_rn(v1.x,v1.x));
        r5 = __fadd_rn(r5, __fmul_rn(v1.y,v1.y));
        r6 = __fadd_rn(r6, __fmul_rn(v1.z,v1.z));
        r7 = __fadd_rn(r7, __fmul_rn(v1.w,v1.w));
    }
    return __fadd_rn(__fadd_rn(__fadd_rn(r0,r1), __fadd_rn(r2,r3)),
                     __fadd_rn(__fadd_rn(r4,r5), __fadd_rn(r6,r7)));
}

__global__ void vq_zero(){ g_loss = 0.0; g_nkmax = 0u; }

__global__ void vq_norms_np(const float* __restrict__ cb){
    int row = blockIdx.x * 256 + threadIdx.x;               // 8192 rows
    const float* a = cb + (size_t)row * DIM;
    float n = __fadd_rn(np_sumsq128(a), np_sumsq128(a + 128));
    g_norms[row] = n;
    atomicMax(&g_nkmax, __float_as_uint(n));
}

// bf16 convert + intra-row 16B-slot permutation: slot s -> s ^ (code&7)
__global__ void vq_prep_wb(const float* __restrict__ cb){
    int t = blockIdx.x * 256 + threadIdx.x;     // 262,144 = 8192 codes x 32 slots
    int code = t >> 5, s = t & 31;
    const float* src = cb + (size_t)code * DIM + s * 8;
    float4 v0 = *(const float4*)(src);
    float4 v1 = *(const float4*)(src + 4);
    u64* dst = (u64*)(g_wb + (size_t)code * DIM + ((s ^ (code & 7)) << 3));
    dst[0] = pack4(v0); dst[1] = pack4(v1);
}

__device__ __forceinline__ void ldsAtomicMinU64(u64* p, u64 v){
    u64 old = *p;
    while (v < old){
        u64 a = old;
        old = atomicCAS(p, a, v);
        if (old == a) break;
    }
}

__global__ __launch_bounds__(256, 4)
void vq_main(const float* __restrict__ z, const float* __restrict__ cb,
             float* __restrict__ out)
{
    __shared__ __align__(16) u16 Wst[2][CCH * DIM];   // 16,384 B double buffer
    __shared__ float nt[KCODES];                      //  4,096 B code norms
    __shared__ float t1[ROWS];
    __shared__ u32   rminU[ROWS];
    __shared__ u32   cnt[ROWS];
    __shared__ u16   cand[ROWS * CAP];                //  3,072 B
    __shared__ u64   bestKey[ROWS];
    __shared__ int   off[ROWS + 1];
    __shared__ int   totalS, ovf;                     // ~25 KB -> 4 blocks/CU

    const int tid     = threadIdx.x;                  // 256 threads, 4 waves
    const int rowbase = blockIdx.x * ROWS;
    const int w       = tid >> 6;                     // wave id -> row group
    const int lane    = tid & 63;
    const int l15     = lane & 15, lg = lane >> 4;
    const int key     = l15 & 7;
    const int urow    = tid >> 2, us = tid & 3;       // update map: 4 thr/row
    double lossAcc = 0.0;

    const float sqnkmax = sqrtf(__uint_as_float(g_nkmax));

    for (int q = 0; q < NQ; ++q){
        const float* rsrc = q ? (const float*)g_resid : z;
        const char*  wbq  = (const char*)g_wb + (size_t)q * KCODES * DIM * 2;

        // issue stage chunk0 -> buf0 (8 KB; drains at the barrier below)
        {
            char* d = (char*)Wst[0];
#pragma unroll
            for (int r = 0; r < 2; ++r){
                int o = (r * 256 + tid) * 16;
                gload_lds16(wbq + o, d + o);
            }
        }
        // nt stage (1024 f32), t1 (np-exact), state reset — overlaps stage0
        *(float4*)(nt + tid * 4) = *(const float4*)(g_norms + q * KCODES + tid * 4);
        if (tid < 128){
            float s = np_sumsq128(rsrc + (size_t)(rowbase + (tid >> 1)) * DIM
                                  + (tid & 1) * 128);
            float o = __shfl_xor(s, 1);
            if (!(tid & 1)) t1[tid >> 1] = __fadd_rn(s, o);
        }
        if (tid < ROWS){
            rminU[tid]   = 0x7f800000u;
            cnt[tid]     = 0u;
            bestKey[tid] = ~0ull;
        }
        // A-frags for this wave's 16 rows from global (L2-hot slice)
        bf16x8 a[8];
        {
            const float* rr = rsrc + (size_t)(rowbase + w * 16 + l15) * DIM + lg * 8;
#pragma unroll
            for (int ks = 0; ks < 8; ++ks){
                float4 v0 = *(const float4*)(rr + ks * 32);
                float4 v1 = *(const float4*)(rr + ks * 32 + 4);
                union { bf16x8 v; u64 p[2]; } u;
                u.p[0] = pack4(v0); u.p[1] = pack4(v1);
                a[ks] = u.v;
            }
        }
        __syncthreads();
        if (tid == 0 && q > 0)
            for (int r = 0; r < ROWS; ++r) lossAcc += (double)t1[r];

        float t1r[4], delta[4], mloc[4], thr[4];
#pragma unroll
        for (int j = 0; j < 4; ++j){
            t1r[j]   = t1[w * 16 + lg * 4 + j];
            delta[j] = 0.02f * sqrtf(t1r[j]) * sqnkmax + 3e-4f;
            mloc[j]  = __int_as_float(0x7f800000);
            thr[j]   = -1.0f;       // no collect until first refresh
        }

        // ---- chunk loop: dbuf staging, register-min, cadence-4 sync ----
        for (int tt = 0; tt < NCH + WARM; ++tt){
            int  cc      = (tt < NCH) ? tt : (tt - NCH);
            int  cur     = tt & 1;
            bool collect = (tt >= WARM);

            if (tt && (tt & 3) == 0){   // refresh thresholds from shared min
#pragma unroll
                for (int j = 0; j < 4; ++j){
                    float g = __uint_as_float(rminU[w * 16 + lg * 4 + j]);
                    thr[j] = fminf(g, mloc[j]) + delta[j];
                }
            }
            if (tt + 1 < NCH + WARM){   // issue-early: next chunk -> buf^1
                int nc = (tt + 1 < NCH) ? tt + 1 : (tt + 1 - NCH);
                const char* src = wbq + (size_t)nc * (CCH * DIM * 2);
                char* d = (char*)Wst[cur ^ 1];
#pragma unroll
                for (int r = 0; r < 2; ++r){
                    int o = (r * 256 + tid) * 16;
                    gload_lds16(src + o, d + o);
                }
            }

            // compute: one 16x16 tile per wave
            float nk = nt[cc * CCH + l15];
            const u16* wrow = Wst[cur] + l15 * DIM;
            f32x4 acc = {0.f, 0.f, 0.f, 0.f};
#pragma unroll
            for (int ks = 0; ks < 8; ++ks){
                bf16x8 b = *(const bf16x8*)(wrow + (((ks * 4 + lg) ^ key) << 3));
                acc = __builtin_amdgcn_mfma_f32_16x16x32_bf16(a[ks], b, acc, 0, 0, 0);
            }
            int codeg = cc * CCH + l15;
#pragma unroll
            for (int j = 0; j < 4; ++j){
                float dest = (t1r[j] + nk) - 2.0f * acc[j];
                mloc[j] = fminf(mloc[j], dest);
                if (collect && dest <= thr[j]){
                    int row = w * 16 + lg * 4 + j;
                    u32 slot = atomicAdd(&cnt[row], 1u);
                    if (slot < CAP) cand[row * CAP + slot] = (u16)codeg;
                }
            }
            if ((tt & 3) == 3){         // publish wave-min to rminU
                float m[4];
#pragma unroll
                for (int j = 0; j < 4; ++j) m[j] = mloc[j];
#pragma unroll
                for (int msk = 1; msk < 16; msk <<= 1)
#pragma unroll
                    for (int j = 0; j < 4; ++j)
                        m[j] = fminf(m[j], __shfl_xor(m[j], msk));
                if (l15 == 0){
#pragma unroll
                    for (int j = 0; j < 4; ++j)
                        atomicMin(&rminU[w * 16 + lg * 4 + j],
                                  __float_as_uint(m[j]));
                }
            }
            __syncthreads();
        }

        // ---- task offsets: 64-lane scan (wave 0) ----
        if (tid < 64){
            int c    = min((int)cnt[tid], CAP);
            int over = cnt[tid] > CAP;
            int x = c;
#pragma unroll
            for (int o = 1; o < 64; o <<= 1){
                int y = __shfl_up(x, o);
                if (tid >= o) x += y;
            }
            off[tid] = x - c;
            if (tid == 63){ off[64] = x; totalS = x; }
#pragma unroll
            for (int o = 1; o < 64; o <<= 1) over |= __shfl_xor(over, o);
            if (tid == 0) ovf = over;
        }
        __syncthreads();

        // ---- exact rescore (round-4-identical serial FMA chain) ----
        int nT = totalS;
        for (int t = tid; t < nT; t += 256){
            int r = 0;
            while (off[r + 1] <= t) ++r;
            int k = (int)cand[r * CAP + (t - off[r])];
            const float* wr = cb + ((size_t)q * KCODES + k) * DIM;
            const float* rr = rsrc + (size_t)(rowbase + r) * DIM;
            float dot = 0.f;
#pragma unroll 4
            for (int i = 0; i < 64; ++i){
                float4 rv = *(const float4*)(rr + i * 4);
                float4 wv = *(const float4*)(wr + i * 4);
                dot = __builtin_fmaf(rv.x, wv.x, dot);
                dot = __builtin_fmaf(rv.y, wv.y, dot);
                dot = __builtin_fmaf(rv.z, wv.z, dot);
                dot = __builtin_fmaf(rv.w, wv.w, dot);
            }
            float d = __fsub_rn(__fadd_rn(t1[r], nt[k]), __fmul_rn(2.0f, dot));
            ldsAtomicMinU64(&bestKey[r], ((u64)__float_as_uint(d) << 32) | (u32)k);
        }
        if (ovf){   // correctness fallback; rare
            for (int r = 0; r < ROWS; ++r){
                if (cnt[r] > CAP){
                    for (int k = tid; k < KCODES; k += 256){
                        const float* wr = cb + ((size_t)q * KCODES + k) * DIM;
                        const float* rr = rsrc + (size_t)(rowbase + r) * DIM;
                        float dot = 0.f;
                        for (int i = 0; i < 64; ++i){
                            float4 rv = *(const float4*)(rr + i * 4);
                            float4 wv = *(const float4*)(wr + i * 4);
                            dot = __builtin_fmaf(rv.x, wv.x, dot);
                            dot = __builtin_fmaf(rv.y, wv.y, dot);
                            dot = __builtin_fmaf(rv.z, wv.z, dot);
                            dot = __builtin_fmaf(rv.w, wv.w, dot);
                        }
                        float d = __fsub_rn(__fadd_rn(t1[r], nt[k]),
                                            __fmul_rn(2.0f, dot));
                        ldsAtomicMinU64(&bestKey[r], ((u64)__float_as_uint(d) << 32) | (u32)k);
                    }
                }
            }
        }
        __syncthreads();

        // indices out (f32)
        if (tid < ROWS)
            out[(size_t)NVEC * DIM + (size_t)(rowbase + tid) * NQ + q] =
                (float)(int)(bestKey[tid] & 0xFFFFFFFFull);

        // update: r_new = fl(r - fl(r + fl(zq - r))) -> g_resid (f32)
        {
            int k = (int)(bestKey[urow] & 0xFFFFFFFFull);
            const float* wrow = cb + ((size_t)q * KCODES + k) * DIM;
            const float* rrow = rsrc + (size_t)(rowbase + urow) * DIM;
            float*       grow = g_resid + (size_t)(rowbase + urow) * DIM;
#pragma unroll
            for (int j = 0; j < 16; ++j){
                int d0 = us * 4 + j * 16;
                float4 r4 = *(const float4*)(rrow + d0);
                float4 wv = *(const float4*)(wrow + d0);
                float4 rn;
                rn.x = __fsub_rn(r4.x, __fadd_rn(r4.x, __fsub_rn(wv.x, r4.x)));
                rn.y = __fsub_rn(r4.y, __fadd_rn(r4.y, __fsub_rn(wv.y, r4.y)));
                rn.z = __fsub_rn(r4.z, __fadd_rn(r4.z, __fsub_rn(wv.z, r4.z)));
                rn.w = __fsub_rn(r4.w, __fadd_rn(r4.w, __fsub_rn(wv.w, r4.w)));
                *(float4*)(grow + d0) = rn;
            }
        }
        __syncthreads();   // g_resid visible block-wide for next q
    }

    // final residual norm (r_8) -> loss
    if (tid < 128){
        float s = np_sumsq128(g_resid + (size_t)(rowbase + (tid >> 1)) * DIM
                              + (tid & 1) * 128);
        float o = __shfl_xor(s, 1);
        if (!(tid & 1)) t1[tid >> 1] = __fadd_rn(s, o);
    }
    __syncthreads();
    if (tid == 0){
        for (int r = 0; r < ROWS; ++r) lossAcc += (double)t1[r];
        atomicAdd(&g_loss, lossAcc);
    }

    // recon out (f32): z - r_final
#pragma unroll
    for (int l = 0; l < 16; ++l){
        int i = l * 256 + tid;
        int row = i >> 6, c4 = i & 63;
        size_t base = (size_t)(rowbase + row) * DIM + c4 * 4;
        float4 zv = *(const float4*)(z + base);
        float4 rv = *(const float4*)(g_resid + base);
        float4 ov;
        ov.x = __fsub_rn(zv.x, rv.x);
        ov.y = __fsub_rn(zv.y, rv.y);
        ov.z = __fsub_rn(zv.z, rv.z);
        ov.w = __fsub_rn(zv.w, rv.w);
        *(float4*)(out + base) = ov;
    }
}

__global__ void vq_loss_final(float* __restrict__ out){
    if (threadIdx.x == 0 && blockIdx.x == 0){
        double m = 1.25 * g_loss / ((double)NVEC * (double)DIM);
        out[(size_t)NVEC * DIM + (size_t)NVEC * NQ] = (float)m;
    }
}

extern "C" void kernel_launch(void* const* d_in, const int* in_sizes, int n_in,
                              void* d_out, int out_size, void* d_ws, size_t ws_size,
                              hipStream_t stream) {
    (void)in_sizes; (void)n_in; (void)out_size; (void)d_ws; (void)ws_size;
    const float* z  = (const float*)d_in[0];
    const float* cb = (const float*)d_in[1];
    float* out = (float*)d_out;

    hipLaunchKernelGGL(vq_zero,       dim3(1),    dim3(1),   0, stream);
    hipLaunchKernelGGL(vq_norms_np,   dim3(32),   dim3(256), 0, stream, cb);
    hipLaunchKernelGGL(vq_prep_wb,    dim3(1024), dim3(256), 0, stream, cb);
    hipLaunchKernelGGL(vq_main,       dim3(NVEC / ROWS), dim3(256), 0, stream, z, cb, out);
    hipLaunchKernelGGL(vq_loss_final, dim3(1),    dim3(64),  0, stream, out);
}